// Round 1
// baseline (492.821 us; speedup 1.0000x reference)
//
#include <hip/hip_runtime.h>
#include <math.h>

// Problem constants (from reference setup_inputs)
constexpr int N  = 8;
constexpr int C  = 32;
constexpr int H  = 256;
constexpr int W  = 256;
constexpr int HU = 512;   // upsampled H
constexpr int WU = 512;   // upsampled W

// Per-axis decomposition of (grid_sample bilinear) o (upsample2x bilinear):
// a continuous coordinate into the virtual upsampled axis collapses to a
// 3-consecutive-texel window of the ORIGINAL axis with 3 merged weights.
struct Axis {
    int   base;          // window base in original axis, in [0, n_in-3]
    float w0, w1, w2;    // weights for base, base+1, base+2
};

__device__ __forceinline__ Axis make_axis(float coord, int n_in, int n_up) {
    float c0f = floorf(coord);
    float t   = coord - c0f;         // grid_sample frac weight
    int   u0  = (int)c0f;            // upsampled-axis corner a

    float w3_0 = 0.f, w3_1 = 0.f, w3_2 = 0.f;
    int rb = 0;

    #pragma unroll
    for (int k = 0; k < 2; ++k) {
        int   yu    = u0 + k;
        float Wc    = (k == 0) ? (1.0f - t) : t;      // grid_sample corner weight
        bool  valid = (yu >= 0) && (yu < n_up);       // zero-padding mask

        // upsample2x source: s = (yu+0.5)/2 - 0.5, clamped >= 0
        float s  = fmaxf(0.5f * (float)yu - 0.25f, 0.0f);
        int   r0 = (int)s;                            // floor (s >= 0)
        r0 = min(r0, n_in - 1);                       // keep in-bounds for wild yu
        float wu = s - (float)r0;
        int   r1 = min(r0 + 1, n_in - 1);

        float w0 = valid ? Wc * (1.0f - wu) : 0.0f;
        float w1 = valid ? Wc * wu          : 0.0f;

        if (k == 0) rb = min(r0, n_in - 3);           // window base from corner a

        int s0 = min(max(r0 - rb, 0), 2);
        int s1 = min(max(r1 - rb, 0), 2);
        // branchless scatter into 3 slots (keeps everything in registers)
        w3_0 += (s0 == 0) ? w0 : 0.0f;
        w3_1 += (s0 == 1) ? w0 : 0.0f;
        w3_2 += (s0 == 2) ? w0 : 0.0f;
        w3_0 += (s1 == 0) ? w1 : 0.0f;
        w3_1 += (s1 == 1) ? w1 : 0.0f;
        w3_2 += (s1 == 2) ? w1 : 0.0f;
    }

    Axis ax;
    ax.base = rb;
    ax.w0 = w3_0; ax.w1 = w3_1; ax.w2 = w3_2;
    return ax;
}

__global__ __launch_bounds__(256)
void fused_up_affine_sample(const float* __restrict__ x,
                            const float* __restrict__ theta,
                            float* __restrict__ out) {
    int tid = blockIdx.x * 256 + threadIdx.x;   // one thread per (n, ho, wo)
    int wo = tid & (WU - 1);
    int ho = (tid >> 9) & (HU - 1);
    int n  = tid >> 18;

    // affine grid (align with reference: xs=(2w+1)/W-1, ys=(2h+1)/H-1)
    float gx = (2.0f * (float)wo + 1.0f) * (1.0f / (float)WU) - 1.0f;
    float gy = (2.0f * (float)ho + 1.0f) * (1.0f / (float)HU) - 1.0f;

    const float* th = theta + n * 6;
    float ox = th[0] * gx + th[1] * gy + th[2];
    float oy = th[3] * gx + th[4] * gy + th[5];

    // grid_sample continuous coords into the (virtual) upsampled image
    float ix = ((ox + 1.0f) * (float)WU - 1.0f) * 0.5f;
    float iy = ((oy + 1.0f) * (float)HU - 1.0f) * 0.5f;

    Axis axx = make_axis(ix, W, WU);
    Axis axy = make_axis(iy, H, HU);

    const float* xb = x + (size_t)n * C * H * W + (size_t)axy.base * W + axx.base;
    float*       ob = out + (size_t)n * C * HU * WU + (size_t)ho * WU + wo;

    float hw0 = axx.w0, hw1 = axx.w1, hw2 = axx.w2;
    float vw0 = axy.w0, vw1 = axy.w1, vw2 = axy.w2;

    #pragma unroll 4
    for (int c = 0; c < C; ++c) {
        const float* p = xb + (size_t)c * (H * W);
        float r0 = p[0      ] * hw0 + p[1        ] * hw1 + p[2        ] * hw2;
        float r1 = p[W      ] * hw0 + p[W + 1    ] * hw1 + p[W + 2    ] * hw2;
        float r2 = p[2 * W  ] * hw0 + p[2 * W + 1] * hw1 + p[2 * W + 2] * hw2;
        ob[(size_t)c * (HU * WU)] = vw0 * r0 + vw1 * r1 + vw2 * r2;
    }
}

extern "C" void kernel_launch(void* const* d_in, const int* in_sizes, int n_in,
                              void* d_out, int out_size, void* d_ws, size_t ws_size,
                              hipStream_t stream) {
    const float* x     = (const float*)d_in[0];
    const float* theta = (const float*)d_in[1];
    float*       out   = (float*)d_out;

    int total_threads = N * HU * WU;            // one thread per (n, ho, wo)
    int blocks = total_threads / 256;           // 8192
    fused_up_affine_sample<<<blocks, 256, 0, stream>>>(x, theta, out);
}

// Round 2
// 469.105 us; speedup vs baseline: 1.0506x; 1.0506x over previous
//
#include <hip/hip_runtime.h>
#include <math.h>

// Problem constants (from reference setup_inputs)
constexpr int N  = 8;
constexpr int C  = 32;
constexpr int H  = 256;
constexpr int W  = 256;
constexpr int HU = 512;   // upsampled H
constexpr int WU = 512;   // upsampled W

constexpr int TILE = 16;  // 16x16 output tile per 256-thread block

// Per-axis decomposition of (grid_sample bilinear) o (upsample2x bilinear):
// a continuous coordinate into the virtual upsampled axis collapses to a
// 3-consecutive-texel window of the ORIGINAL axis with 3 merged weights.
struct Axis {
    int   base;          // window base in original axis, in [0, n_in-3]
    float w0, w1, w2;    // weights for base, base+1, base+2
};

__device__ __forceinline__ Axis make_axis(float coord, int n_in, int n_up) {
    float c0f = floorf(coord);
    float t   = coord - c0f;         // grid_sample frac weight
    int   u0  = (int)c0f;            // upsampled-axis corner a

    float w3_0 = 0.f, w3_1 = 0.f, w3_2 = 0.f;
    int rb = 0;

    #pragma unroll
    for (int k = 0; k < 2; ++k) {
        int   yu    = u0 + k;
        float Wc    = (k == 0) ? (1.0f - t) : t;      // grid_sample corner weight
        bool  valid = (yu >= 0) && (yu < n_up);       // zero-padding mask

        // upsample2x source: s = (yu+0.5)/2 - 0.5, clamped >= 0
        float s  = fmaxf(0.5f * (float)yu - 0.25f, 0.0f);
        int   r0 = (int)s;                            // floor (s >= 0)
        r0 = min(r0, n_in - 1);                       // keep in-bounds for wild yu
        float wu = s - (float)r0;
        int   r1 = min(r0 + 1, n_in - 1);

        float w0 = valid ? Wc * (1.0f - wu) : 0.0f;
        float w1 = valid ? Wc * wu          : 0.0f;

        if (k == 0) rb = min(r0, n_in - 3);           // window base from corner a

        int s0 = min(max(r0 - rb, 0), 2);
        int s1 = min(max(r1 - rb, 0), 2);
        // branchless scatter into 3 slots (keeps everything in registers)
        w3_0 += (s0 == 0) ? w0 : 0.0f;
        w3_1 += (s0 == 1) ? w0 : 0.0f;
        w3_2 += (s0 == 2) ? w0 : 0.0f;
        w3_0 += (s1 == 0) ? w1 : 0.0f;
        w3_1 += (s1 == 1) ? w1 : 0.0f;
        w3_2 += (s1 == 2) ? w1 : 0.0f;
    }

    Axis ax;
    ax.base = rb;
    ax.w0 = w3_0; ax.w1 = w3_1; ax.w2 = w3_2;
    return ax;
}

__global__ __launch_bounds__(256)
void fused_up_affine_sample(const float* __restrict__ x,
                            const float* __restrict__ theta,
                            float* __restrict__ out) {
    // 2D tile mapping: wave = 16x4 output patch -> gather footprint per
    // wave-load is ~4 rows x ~2 cache lines instead of ~64 scattered lines.
    int wo = blockIdx.x * TILE + (threadIdx.x & (TILE - 1));
    int ho = blockIdx.y * TILE + (threadIdx.x >> 4);
    int n  = blockIdx.z;                          // block-uniform -> SGPR theta

    // affine grid (reference: xs=(2w+1)/W-1, ys=(2h+1)/H-1)
    float gx = (2.0f * (float)wo + 1.0f) * (1.0f / (float)WU) - 1.0f;
    float gy = (2.0f * (float)ho + 1.0f) * (1.0f / (float)HU) - 1.0f;

    const float* th = theta + n * 6;
    float ox = th[0] * gx + th[1] * gy + th[2];
    float oy = th[3] * gx + th[4] * gy + th[5];

    // grid_sample continuous coords into the (virtual) upsampled image
    float ix = ((ox + 1.0f) * (float)WU - 1.0f) * 0.5f;
    float iy = ((oy + 1.0f) * (float)HU - 1.0f) * 0.5f;

    Axis axx = make_axis(ix, W, WU);
    Axis axy = make_axis(iy, H, HU);

    const float* xb = x + (size_t)n * C * H * W + (size_t)axy.base * W + axx.base;
    float*       ob = out + (size_t)n * C * HU * WU + (size_t)ho * WU + wo;

    float hw0 = axx.w0, hw1 = axx.w1, hw2 = axx.w2;
    float vw0 = axy.w0, vw1 = axy.w1, vw2 = axy.w2;

    #pragma unroll 4
    for (int c = 0; c < C; ++c) {
        const float* p = xb + (size_t)c * (H * W);
        float r0 = p[0      ] * hw0 + p[1        ] * hw1 + p[2        ] * hw2;
        float r1 = p[W      ] * hw0 + p[W + 1    ] * hw1 + p[W + 2    ] * hw2;
        float r2 = p[2 * W  ] * hw0 + p[2 * W + 1] * hw1 + p[2 * W + 2] * hw2;
        ob[(size_t)c * (HU * WU)] = vw0 * r0 + vw1 * r1 + vw2 * r2;
    }
}

extern "C" void kernel_launch(void* const* d_in, const int* in_sizes, int n_in,
                              void* d_out, int out_size, void* d_ws, size_t ws_size,
                              hipStream_t stream) {
    const float* x     = (const float*)d_in[0];
    const float* theta = (const float*)d_in[1];
    float*       out   = (float*)d_out;

    dim3 grid(WU / TILE, HU / TILE, N);   // 32 x 32 x 8 = 8192 blocks
    fused_up_affine_sample<<<grid, 256, 0, stream>>>(x, theta, out);
}